// Round 16
// baseline (85.089 us; speedup 1.0000x reference)
//
#include <hip/hip_runtime.h>

#define BB 512
#define TT 512
#define KK 128
#define CS 160   // chain stride in shorts: 320B = 80 dw == +16 banks per chain

typedef __attribute__((ext_vector_type(8))) short short8;   // 8 x bf16 bits
typedef __attribute__((ext_vector_type(4))) float f32x4;

// f32 -> bf16 bits, round-to-nearest-even (finite values)
__device__ __forceinline__ unsigned short f2bf(float f) {
  unsigned u = __float_as_uint(f);
  unsigned r = ((u >> 16) & 1u) + 0x7fffu;
  return (unsigned short)((u + r) >> 16);
}
__device__ __forceinline__ float bf2f(unsigned short h) {
  return __uint_as_float(((unsigned)h) << 16);
}
// Drain LDS ops only; global prefetch loads stay in flight across the barrier.
__device__ __forceinline__ void lds_barrier() {
  asm volatile("s_waitcnt lgkmcnt(0)\n\ts_barrier" ::: "memory");
}

// K1: one block per (batch-pair, direction). 256 threads = 4 waves.
// TWO chains (batches 2p, 2p+1) packed into MFMA A-rows by parity:
//   A[row][k] = state[row&1][k]   (A layout: row = lane&15, k = 8*(lane>>4)+e)
// Wave wv computes col-tiles {2wv, 2wv+1} for both chains: 8 MFMAs/wave/step
// as 2-deep chains (aP,aQ independent, +1 add) to halve MFMA dep latency.
// D layout (HW-verified): col = lane&15, row = 4*(lane>>4)+reg -> chain=reg&1.
// Lane (lg,lc) finalizes chain cW=lg&1, col jW=32wv+16(lg>>1)+lc.
// Critical-path diet vs R15:
//  - ex = exp2(pot*C) PRECOMPUTED one step ahead (pot already in the next
//    phase register); scale 2^-d applied as SALU-built float -> epilogue is
//    two VALU muls after the MFMA result.
//  - v_cvt_pk_bf16_f32 (1 op, RNE) replaces the 4-op manual f2bf round.
//  - chain stride CS=160: conflict-free reads (R15, verified 9.4e6 -> 0).
//  - d_c from readlane of state[c][0]'s bf16 exponent (no dbuf LDS ops).
// Scaled bf16 state, lagged power-of-2 rescale: stored_new = matvec *
// exp2(pot*C) * 2^-d_c; M_c += d_c; true value = stored * 2^M_c.
// dir=0 fwd: w_t = u_t.(E^T w_{t-1}), t=1..256; dir=1 bwd: y_{t-1} =
// u_{t-1}.(E y_t), t=510..257, then y = E y_257 (no u). K2 combines.
__global__ __launch_bounds__(256, 2) void crf_half_kernel(
    const float* __restrict__ pot, const int* __restrict__ tags,
    const float* __restrict__ trans, unsigned short* __restrict__ wsv,
    float4* __restrict__ wsm) {
  const float C = 1.4426950408889634f;    // 1/ln2
  const int bid = blockIdx.x;
  const int pair = bid >> 1, dir = bid & 1;
  const int tid = threadIdx.x;            // 0..255
  const int lane = tid & 63;
  const int wv = tid >> 6;                // wave 0..3 -> col-tiles 2wv,2wv+1
  const int lg = lane >> 4;               // lane group 0..3
  const int lc = lane & 15;               // column within 16-tile

  __shared__ alignas(16) unsigned short sbuf[2][2][CS];  // [parity][chain][j]
  __shared__ float red[4];

  // ---- sequence scores for both batches (fwd blocks only; bwd writes 0) ----
  float sc = 0.f;
  if (dir == 0) {
    int bb = 2 * pair + (tid >> 7);       // threads 0-127 -> b0, 128-255 -> b1
    int base = 4 * (tid & 127);
    const float* pbs = pot + (size_t)bb * TT * KK;
    int4 tg = *(const int4*)&tags[bb * TT + base];
    sc = pbs[(size_t)(base + 0) * KK + tg.x] + pbs[(size_t)(base + 1) * KK + tg.y]
       + pbs[(size_t)(base + 2) * KK + tg.z] + pbs[(size_t)(base + 3) * KK + tg.w];
    sc += trans[tg.x * KK + tg.y] + trans[tg.y * KK + tg.z] +
          trans[tg.z * KK + tg.w];
    if (base + 4 < TT) sc += trans[tg.w * KK + tags[bb * TT + base + 4]];
  }
  #pragma unroll
  for (int off = 32; off; off >>= 1) sc += __shfl_xor(sc, off, 64);
  if (lane == 0) red[wv] = sc;            // b0 partials red[0,1]; b1 red[2,3]

  // ---- B fragments: 2 tiles x 4 k-chunks (bwd: transposed E) ----
  short8 Bf0[4], Bf1[4];
  const int jT0 = 32 * wv + lc, jT1 = jT0 + 16;
  #pragma unroll
  for (int kc = 0; kc < 4; ++kc) {
    #pragma unroll
    for (int e = 0; e < 8; ++e) {
      int k = 32 * kc + 8 * lg + e;
      float t0 = (dir == 0) ? trans[k * KK + jT0] : trans[jT0 * KK + k];
      float t1 = (dir == 0) ? trans[k * KK + jT1] : trans[jT1 * KK + k];
      Bf0[kc][e] = (short)f2bf(__builtin_amdgcn_exp2f(t0 * C));
      Bf1[kc][e] = (short)f2bf(__builtin_amdgcn_exp2f(t1 * C));
    }
  }

  // ---- init: state[0][c] = u_{t0} of batch 2p+c (fwd t0=0, bwd t0=511) ----
  {
    int c = tid >> 7, j = tid & 127;
    int bb = 2 * pair + c;
    int ri = dir ? (TT - 1) : 0;
    float w0 = __builtin_amdgcn_exp2f(pot[(size_t)bb * TT * KK +
                                          (size_t)ri * KK + j] * C);
    sbuf[0][c][j] = f2bf(w0);
  }
  __syncthreads();

  const int nst = dir ? 255 : 256;
  const int r0 = dir ? (TT - 2) : 1;
  const int st = dir ? -1 : 1;
  // per-lane epilogue identity
  const int cW = lg & 1;                        // chain this lane finalizes
  const int jW = 32 * wv + 16 * (lg >> 1) + lc; // its output column
  const float* pp = pot + (size_t)(2 * pair + cW) * TT * KK + jW;
  const int crA = lc & 1;                       // A-row chain parity (reads)
  int Mi0 = 0, Mi1 = 0;
  const f32x4 kZero = {0.f, 0.f, 0.f, 0.f};

  // 4-phase pot pipeline, one float per phase
  float p0 = pp[(size_t)(r0 + 0 * st) * KK];
  float p1 = pp[(size_t)(r0 + 1 * st) * KK];
  float p2 = pp[(size_t)(r0 + 2 * st) * KK];
  float p3 = pp[(size_t)(r0 + 3 * st) * KK];

  // ex for step 0, precomputed (pot row r0 is step 0's u-factor)
  float exA = __builtin_amdgcn_exp2f(p0 * C);

  // step(it, q = phase it&3 register, qn = phase (it+1)&3 register)
  auto step = [&](int it, float& q, const float& qn) {
    const int p = it & 1, wr = p ^ 1;
    const unsigned short* sp = &sbuf[p][crA][8 * lg];
    short8 A0 = *(const short8*)(sp);        // k =      8lg+e
    short8 A1 = *(const short8*)(sp + 32);   // k = 32 + 8lg+e
    short8 A2 = *(const short8*)(sp + 64);
    short8 A3 = *(const short8*)(sp + 96);
    // scale exponents from state[c][0] bf16 bits (lanes 0/1), via SALU
    int e0 = (int)(unsigned short)A0[0];
    int d0 = ((__builtin_amdgcn_readlane(e0, 0) >> 7) & 0xFF) - 127;
    int d1 = ((__builtin_amdgcn_readlane(e0, 1) >> 7) & 0xFF) - 127;
    float ex = exA;                          // exp2(pot_it * C), from last step
    // precompute ex for the NEXT step (its pot already resides in qn);
    // bwd's final step uses u=1 (y = E z, no u factor)
    const bool nextLast = (dir == 1) && (it + 1 == nst - 1);
    float pn = nextLast ? 0.f : qn;
    exA = __builtin_amdgcn_exp2f(pn * C);
    float cp0 = q;  (void)cp0;
    int rn = r0 + st * (it + 4);             // fwd <=260, bwd >=252: in range
    q = pp[(size_t)rn * KK];
    f32x4 aP0, aQ0, aP1, aQ1;
    __builtin_amdgcn_s_setprio(1);
    aP0 = __builtin_amdgcn_mfma_f32_16x16x32_bf16(A3, Bf0[3], kZero, 0, 0, 0);
    aQ0 = __builtin_amdgcn_mfma_f32_16x16x32_bf16(A2, Bf0[2], kZero, 0, 0, 0);
    aP1 = __builtin_amdgcn_mfma_f32_16x16x32_bf16(A3, Bf1[3], kZero, 0, 0, 0);
    aQ1 = __builtin_amdgcn_mfma_f32_16x16x32_bf16(A2, Bf1[2], kZero, 0, 0, 0);
    aP0 = __builtin_amdgcn_mfma_f32_16x16x32_bf16(A1, Bf0[1], aP0, 0, 0, 0);
    aQ0 = __builtin_amdgcn_mfma_f32_16x16x32_bf16(A0, Bf0[0], aQ0, 0, 0, 0);
    aP1 = __builtin_amdgcn_mfma_f32_16x16x32_bf16(A1, Bf1[1], aP1, 0, 0, 0);
    aQ1 = __builtin_amdgcn_mfma_f32_16x16x32_bf16(A0, Bf1[0], aQ1, 0, 0, 0);
    __builtin_amdgcn_s_setprio(0);
    // rows alternate chains (row parity = reg&1); take reg cW, tile lg>>1
    float z0 = (cW ? aP0[1] : aP0[0]) + (cW ? aQ0[1] : aQ0[0]);
    float z1 = (cW ? aP1[1] : aP1[0]) + (cW ? aQ1[1] : aQ1[0]);
    float z = (lg & 2) ? z1 : z0;
    int dc = cW ? d1 : d0;
    float scl = __uint_as_float((unsigned)(127 - dc) << 23);  // 2^-dc (SALU)
    float v = z * ex * scl;
    Mi0 += d0; Mi1 += d1;
    unsigned bfv;
    asm("v_cvt_pk_bf16_f32 %0, %1, %2" : "=v"(bfv) : "v"(v), "v"(0.f));
    sbuf[wr][cW][jW] = (unsigned short)bfv;
    lds_barrier();   // lgkmcnt(0)+s_barrier; global loads stay in flight
  };

  const int nq = nst >> 2;                   // fwd 64, bwd 63
  for (int itq = 0; itq < nq; ++itq) {
    int it = itq << 2;
    step(it + 0, p0, p1);
    step(it + 1, p1, p2);
    step(it + 2, p2, p3);
    step(it + 3, p3, p0);   // p0 already reloaded (row it+4) at step it+0
  }
  if (dir == 1) {                            // bwd tail: steps 252..254
    step(252, p0, p1);
    step(253, p1, p2);
    step(254, p2, p3);
  }

  // ---- export final state + M + scores ----
  const int fin = nst & 1;                   // fwd parity 0, bwd parity 1
  {
    int c = tid >> 7, j = tid & 127;
    wsv[((size_t)bid * 2 + c) * KK + j] = sbuf[fin][c][j];
  }
  if (tid == 0) {
    float4 m;
    m.x = (float)Mi0; m.y = (float)Mi1;
    m.z = red[0] + red[1]; m.w = red[2] + red[3];
    wsm[bid] = m;
  }
}

// K2: combine. One wave per batch: Z*2^(Mf+Mb) = wF . yB.
__global__ __launch_bounds__(256) void crf_combine_kernel(
    const unsigned short* __restrict__ wsv, const float4* __restrict__ wsm,
    float* __restrict__ out) {
  const float LN2 = 0.6931471805599453f;
  const int tid = threadIdx.x;
  const int lane = tid & 63, wid = tid >> 6;
  const int b = blockIdx.x * 4 + wid;
  const int pair = b >> 1, c = b & 1;
  const unsigned short* wf = wsv + ((size_t)(2 * pair + 0) * 2 + c) * KK;
  const unsigned short* yb = wsv + ((size_t)(2 * pair + 1) * 2 + c) * KK;
  float pr = bf2f(wf[lane]) * bf2f(yb[lane]) +
             bf2f(wf[lane + 64]) * bf2f(yb[lane + 64]);
  #pragma unroll
  for (int off = 32; off; off >>= 1) pr += __shfl_xor(pr, off, 64);
  if (lane == 0) {
    float4 mf = wsm[2 * pair + 0];           // fwd: {M0, M1, sc0, sc1}
    float4 mb = wsm[2 * pair + 1];           // bwd: {M0, M1, 0, 0}
    float Mf = c ? mf.y : mf.x;
    float Mb = c ? mb.y : mb.x;
    float scv = c ? mf.w : mf.z;
    out[b] = scv - (Mf + Mb + __builtin_amdgcn_logf(pr)) * LN2;
  }
}

extern "C" void kernel_launch(void* const* d_in, const int* in_sizes, int n_in,
                              void* d_out, int out_size, void* d_ws, size_t ws_size,
                              hipStream_t stream) {
  const float* pot = (const float*)d_in[0];
  const int* tags = (const int*)d_in[1];
  const float* trans = (const float*)d_in[2];
  float* out = (float*)d_out;
  unsigned short* wsv = (unsigned short*)d_ws;            // 512 x 2 x 128 bf16
  float4* wsm = (float4*)((char*)d_ws + (size_t)512 * 2 * KK * 2);
  crf_half_kernel<<<2 * BB / 2, 256, 0, stream>>>(pot, tags, trans, wsv, wsm);
  crf_combine_kernel<<<BB / 4, 256, 0, stream>>>(wsv, wsm, out);
}